// Round 1
// baseline (1596.673 us; speedup 1.0000x reference)
//
#include <hip/hip_runtime.h>

#define DEPTH 18
#define NN ((1 << DEPTH) - 1)   // 262143

__device__ __forceinline__ float sigm_(float x) { return 1.f / (1.f + __expf(-x)); }
// safe tanh via exp2-based expf: no NaN at +/-inf
__device__ __forceinline__ float tanh_(float x) { float e = __expf(2.f * x); return 1.f - 2.f / (e + 1.f); }

// ---------------------------------------------------------------------------
// Tiled level kernel: 32 nodes per block, 256 threads.  Used for levels with
// n >= 2048 (always full tiles).  Fuses: emb gather, x-projections, child-sum
// recurrence GEMMs, gates, h/c store, and the 128->5 output head.
//
// Thread tile: tn = t&7 -> 4 nodes, tc = t>>3 -> 4 cols (of 128 gate cols).
// Accumulators: aI/aO/aU (iou), aFx (emb@W_f), aFl/aFr (h_l/h_r @ U_f).
// A operands staged TRANSPOSED in LDS ([k][node], stride 36 words) so the
// inner loop reads one float4 = 4 nodes per instruction, conflict-free.
// B chunk (4 k-rows of [W_iou|U_iou|W_f|U_f] = 1024 cols) staged per 4-k step.
// LDS total ~74 KB -> 2 blocks/CU.
// ---------------------------------------------------------------------------
#define FMA4(ACC, S, B) { ACC[i][0] += (S)*(B).x; ACC[i][1] += (S)*(B).y; \
                          ACC[i][2] += (S)*(B).z; ACC[i][3] += (S)*(B).w; }

__global__ __launch_bounds__(256, 2) void tree_level_tiled(
    const int* __restrict__ xids, const int* __restrict__ msk,
    const float* __restrict__ emb,
    const float* __restrict__ Wiou, const float* __restrict__ Uiou, const float* __restrict__ biou,
    const float* __restrict__ Wf,   const float* __restrict__ Uf,   const float* __restrict__ bfv,
    const float* __restrict__ Wout, const float* __restrict__ bout,
    float* __restrict__ h_ws, float* __restrict__ c_ws, float* __restrict__ outp,
    int s0, int hasChild)
{
    __shared__ __align__(16) float embT[128][36];
    __shared__ __align__(16) float hlT[128][36];
    __shared__ __align__(16) float hrT[128][36];
    __shared__ __align__(16) float Bw[4][1024];
    __shared__ __align__(16) float wout_s[640];
    __shared__ int eidx_s[32];

    const int t  = threadIdx.x;
    const int g0 = s0 + blockIdx.x * 32;

    if (t < 32)  eidx_s[t] = xids[g0 + t] * msk[g0 + t];
    if (t < 160) ((float4*)wout_s)[t] = ((const float4*)Wout)[t];
    __syncthreads();

    {   // stage A operands transposed: [k][node]
        const int n      = t & 31;
        const int c4base = t >> 5;          // 0..7
        const int erow   = eidx_s[n];
        #pragma unroll
        for (int q = 0; q < 4; ++q) {
            const int k = (c4base + 8 * q) * 4;   // 0,4,...,124 (+lane offset)
            float4 v = *(const float4*)(emb + erow * 128 + k);
            embT[k][n] = v.x; embT[k+1][n] = v.y; embT[k+2][n] = v.z; embT[k+3][n] = v.w;
        }
        if (hasChild) {
            const int gl = 2 * (g0 + n) + 1;
            #pragma unroll
            for (int q = 0; q < 4; ++q) {
                const int k = (c4base + 8 * q) * 4;
                float4 v = *(const float4*)(h_ws + gl * 128 + k);
                hlT[k][n] = v.x; hlT[k+1][n] = v.y; hlT[k+2][n] = v.z; hlT[k+3][n] = v.w;
                float4 w = *(const float4*)(h_ws + (gl + 1) * 128 + k);
                hrT[k][n] = w.x; hrT[k+1][n] = w.y; hrT[k+2][n] = w.z; hrT[k+3][n] = w.w;
            }
        }
    }

    float aI[4][4] = {}, aO[4][4] = {}, aU[4][4] = {};
    float aFx[4][4] = {}, aFl[4][4] = {}, aFr[4][4] = {};
    const int tn4 = (t & 7) * 4;
    const int tc4 = (t >> 3) * 4;

    for (int kb = 0; kb < 128; kb += 4) {
        __syncthreads();   // first pass: also covers A staging above
        #pragma unroll
        for (int q = 0; q < 4; ++q) {
            const int idx = q * 256 + t;
            const int rr  = idx >> 8;
            const int c   = (idx & 255) * 4;
            const int k   = kb + rr;
            float4 v;
            if      (c < 384) v = *(const float4*)(Wiou + k * 384 + c);
            else if (c < 768) v = *(const float4*)(Uiou + k * 384 + (c - 384));
            else if (c < 896) v = *(const float4*)(Wf   + k * 128 + (c - 768));
            else              v = *(const float4*)(Uf   + k * 128 + (c - 896));
            *(float4*)&Bw[rr][c] = v;
        }
        __syncthreads();
        #pragma unroll
        for (int kk = 0; kk < 4; ++kk) {
            const int k = kb + kk;
            const float4 e4 = *(const float4*)&embT[k][tn4];
            const float4 bi = *(const float4*)&Bw[kk][tc4];
            const float4 bo = *(const float4*)&Bw[kk][tc4 + 128];
            const float4 bu = *(const float4*)&Bw[kk][tc4 + 256];
            const float* ep = (const float*)&e4;
            if (hasChild) {
                const float4 l4  = *(const float4*)&hlT[k][tn4];
                const float4 r4  = *(const float4*)&hrT[k][tn4];
                const float4 bI2 = *(const float4*)&Bw[kk][tc4 + 384];
                const float4 bO2 = *(const float4*)&Bw[kk][tc4 + 512];
                const float4 bU2 = *(const float4*)&Bw[kk][tc4 + 640];
                const float4 bwf = *(const float4*)&Bw[kk][tc4 + 768];
                const float4 buf = *(const float4*)&Bw[kk][tc4 + 896];
                const float* lp = (const float*)&l4;
                const float* rp = (const float*)&r4;
                #pragma unroll
                for (int i = 0; i < 4; ++i) {
                    const float ev = ep[i], lv = lp[i], rv = rp[i];
                    const float sv = lv + rv;
                    FMA4(aI, ev, bi);  FMA4(aO, ev, bo);  FMA4(aU, ev, bu);
                    FMA4(aI, sv, bI2); FMA4(aO, sv, bO2); FMA4(aU, sv, bU2);
                    FMA4(aFx, ev, bwf);
                    FMA4(aFl, lv, buf); FMA4(aFr, rv, buf);
                }
            } else {
                #pragma unroll
                for (int i = 0; i < 4; ++i) {
                    const float ev = ep[i];
                    FMA4(aI, ev, bi); FMA4(aO, ev, bo); FMA4(aU, ev, bu);
                }
            }
        }
    }
    __syncthreads();   // all embT reads done before reuse as h buffer

    // gates + stores; reuse embT[k][n] as transposed h buffer for out head
    const float4 bi4 = *(const float4*)(biou + tc4);
    const float4 bo4 = *(const float4*)(biou + 128 + tc4);
    const float4 bu4 = *(const float4*)(biou + 256 + tc4);
    const float4 bf4 = *(const float4*)(bfv + tc4);
    const float* bip = (const float*)&bi4;
    const float* bop = (const float*)&bo4;
    const float* bup = (const float*)&bu4;
    const float* bfp = (const float*)&bf4;

    #pragma unroll
    for (int i = 0; i < 4; ++i) {
        const int n = (t & 7) * 4 + i;
        const int g = g0 + n;
        float4 cl4 = make_float4(0.f, 0.f, 0.f, 0.f);
        float4 cr4 = make_float4(0.f, 0.f, 0.f, 0.f);
        if (hasChild) {
            cl4 = *(const float4*)(c_ws + (2 * g + 1) * 128 + tc4);
            cr4 = *(const float4*)(c_ws + (2 * g + 2) * 128 + tc4);
        }
        const float* clp = (const float*)&cl4;
        const float* crp = (const float*)&cr4;
        float4 cv, hv;
        float* cvp = (float*)&cv;
        float* hvp = (float*)&hv;
        #pragma unroll
        for (int j = 0; j < 4; ++j) {
            const float ii = aI[i][j] + bip[j];
            const float oo = aO[i][j] + bop[j];
            const float uu = aU[i][j] + bup[j];
            float fc = 0.f;
            if (hasChild) {
                const float fl = sigm_(aFx[i][j] + aFl[i][j] + bfp[j]);
                const float fr = sigm_(aFx[i][j] + aFr[i][j] + bfp[j]);
                fc = fl * clp[j] + fr * crp[j];
            }
            const float cc = sigm_(ii) * tanh_(uu) + fc;
            const float hh = sigm_(oo) * tanh_(cc);
            cvp[j] = cc; hvp[j] = hh;
        }
        *(float4*)(c_ws + g * 128 + tc4) = cv;
        *(float4*)(h_ws + g * 128 + tc4) = hv;
        embT[tc4][n] = hv.x; embT[tc4+1][n] = hv.y; embT[tc4+2][n] = hv.z; embT[tc4+3][n] = hv.w;
    }
    __syncthreads();
    if (t < 160) {                   // output head: 32 nodes x 5 cols
        const int n = t / 5, cc = t - 5 * n;
        float acc = bout[cc];
        #pragma unroll 8
        for (int k = 0; k < 128; ++k) acc += embT[k][n] * wout_s[k * 5 + cc];
        outp[(g0 + n) * 5 + cc] = acc;
    }
}

// ---------------------------------------------------------------------------
// Streaming level kernel: one block (256 threads) per node, weights straight
// from L2.  Used for small levels (d <= 10, n <= 1024) where the tiled kernel
// would serialize ~20us/level.  These levels always have children (d < 17).
// Combined output vector O[640] = [iou(384) | f_l(128) | f_r(128)].
// Thread t owns cols {t, 256+t, (t<128: 512+t)}.
// ---------------------------------------------------------------------------
__global__ __launch_bounds__(256) void tree_level_small(
    const int* __restrict__ xids, const int* __restrict__ msk,
    const float* __restrict__ emb,
    const float* __restrict__ Wiou, const float* __restrict__ Uiou, const float* __restrict__ biou,
    const float* __restrict__ Wf,   const float* __restrict__ Uf,   const float* __restrict__ bfv,
    const float* __restrict__ Wout, const float* __restrict__ bout,
    float* __restrict__ h_ws, float* __restrict__ c_ws, float* __restrict__ outp,
    int s0)
{
    __shared__ __align__(16) float emb_s[128], hs_s[128], hl_s[128], hr_s[128];
    __shared__ __align__(16) float cl_s[128], cr_s[128];
    __shared__ __align__(16) float O_s[640];

    const int g  = s0 + blockIdx.x;
    const int t  = threadIdx.x;
    const int ei = xids[g] * msk[g];
    const int gl = 2 * g + 1, gr = 2 * g + 2;

    if      (t < 32)  ((float4*)emb_s)[t]      = ((const float4*)(emb  + ei * 128))[t];
    else if (t < 64)  ((float4*)hl_s)[t - 32]  = ((const float4*)(h_ws + gl * 128))[t - 32];
    else if (t < 96)  ((float4*)hr_s)[t - 64]  = ((const float4*)(h_ws + gr * 128))[t - 64];
    else if (t < 128) ((float4*)cl_s)[t - 96]  = ((const float4*)(c_ws + gl * 128))[t - 96];
    else if (t < 160) ((float4*)cr_s)[t - 128] = ((const float4*)(c_ws + gr * 128))[t - 128];
    __syncthreads();
    if (t < 128) hs_s[t] = hl_s[t] + hr_s[t];
    __syncthreads();

    // column parameter setup
    const int c0 = t;            // 0..255 -> always iou region
    const int c1 = 256 + t;      // 256..511
    const float* B10 = Wiou + c0;
    const float* B20 = Uiou + c0;
    const float *B11, *B21, *A21;
    int st1;
    if (c1 < 384) { B11 = Wiou + c1;       B21 = Uiou + c1;       st1 = 384; A21 = hs_s; }
    else          { B11 = Wf + (c1 - 384); B21 = Uf + (c1 - 384); st1 = 128; A21 = hl_s; }
    const int c2c = (t < 128) ? t : 0;     // f_r col (clamped for idle threads)
    const float* B12 = Wf + c2c;
    const float* B22 = Uf + c2c;

    float a0 = 0.f, a1 = 0.f, a2 = 0.f;
    #pragma unroll 4
    for (int k = 0; k < 128; ++k) {
        const float e = emb_s[k];
        a0 += e * B10[k * 384];
        a0 += hs_s[k] * B20[k * 384];
        a1 += e * B11[k * st1];
        a1 += A21[k] * B21[k * st1];
        a2 += e * B12[k * 128];
        a2 += hr_s[k] * B22[k * 128];
    }
    O_s[c0] = a0;
    O_s[c1] = a1;
    if (t < 128) O_s[512 + t] = a2;
    __syncthreads();

    if (t < 128) {
        const int k = t;
        const float ii = O_s[k]       + biou[k];
        const float oo = O_s[128 + k] + biou[128 + k];
        const float uu = O_s[256 + k] + biou[256 + k];
        const float fl = sigm_(O_s[384 + k] + bfv[k]);
        const float fr = sigm_(O_s[512 + k] + bfv[k]);
        const float fc = fl * cl_s[k] + fr * cr_s[k];
        const float cc = sigm_(ii) * tanh_(uu) + fc;
        const float hh = sigm_(oo) * tanh_(cc);
        c_ws[(size_t)g * 128 + k] = cc;
        h_ws[(size_t)g * 128 + k] = hh;
        O_s[k] = hh;   // safe: each thread reads its own O_s slots first
    }
    __syncthreads();
    if (t < 5) {
        float acc = bout[t];
        for (int k = 0; k < 128; ++k) acc += O_s[k] * Wout[k * 5 + t];
        outp[(size_t)g * 5 + t] = acc;
    }
}

extern "C" void kernel_launch(void* const* d_in, const int* in_sizes, int n_in,
                              void* d_out, int out_size, void* d_ws, size_t ws_size,
                              hipStream_t stream)
{
    (void)in_sizes; (void)n_in; (void)out_size; (void)ws_size;
    const int*   xids = (const int*)d_in[0];
    const int*   msk  = (const int*)d_in[1];
    const float* emb  = (const float*)d_in[2];
    const float* Wiou = (const float*)d_in[3];
    const float* Uiou = (const float*)d_in[4];
    const float* biou = (const float*)d_in[5];
    const float* Wf   = (const float*)d_in[6];
    const float* Uf   = (const float*)d_in[7];
    const float* bfv  = (const float*)d_in[8];
    const float* Wout = (const float*)d_in[9];
    const float* bout = (const float*)d_in[10];
    float* outp = (float*)d_out;
    float* h_ws = (float*)d_ws;                       // N x 128 f32
    float* c_ws = h_ws + (size_t)NN * 128;            // N x 128 f32  (268 MB total)

    // big levels: tiled kernel (leaf d=17 first, down to d=11)
    for (int d = DEPTH - 1; d >= 11; --d) {
        const int s0 = (1 << d) - 1;
        const int n  = 1 << d;
        hipLaunchKernelGGL(tree_level_tiled, dim3(n / 32), dim3(256), 0, stream,
            xids, msk, emb, Wiou, Uiou, biou, Wf, Uf, bfv, Wout, bout,
            h_ws, c_ws, outp, s0, (d < DEPTH - 1) ? 1 : 0);
    }
    // small levels: one block per node
    for (int d = 10; d >= 0; --d) {
        const int s0 = (1 << d) - 1;
        const int n  = 1 << d;
        hipLaunchKernelGGL(tree_level_small, dim3(n), dim3(256), 0, stream,
            xids, msk, emb, Wiou, Uiou, biou, Wf, Uf, bfv, Wout, bout,
            h_ws, c_ws, outp, s0);
    }
}

// Round 3
// 529.688 us; speedup vs baseline: 3.0144x; 3.0144x over previous
//
#include <hip/hip_runtime.h>

#define DEPTH 18
#define NN ((1 << DEPTH) - 1)   // 262143

typedef __attribute__((ext_vector_type(8))) short short8;
typedef __attribute__((ext_vector_type(4))) float f32x4;

__device__ __forceinline__ float sigm_(float x) { return 1.f / (1.f + __expf(-x)); }
__device__ __forceinline__ float tanh_(float x) { float e = __expf(2.f * x); return 1.f - 2.f / (e + 1.f); }
__device__ __forceinline__ unsigned short f2bf(float f) {
    union { float f; unsigned int u; } v; v.f = f;
    unsigned int r = (v.u + 0x7fffu + ((v.u >> 16) & 1u)) >> 16;
    return (unsigned short)r;
}
__device__ __forceinline__ float bf2f(unsigned short h) {
    union { unsigned int u; float f; } v; v.u = ((unsigned int)h) << 16; return v.f;
}

// ---------------------------------------------------------------------------
// Prep: emb table -> bf16; packed bf16 B matrix.
// bpack layout: [chunk c (8)][col j (512)][k-local (32)], contiguous bf16.
//   col j<384  : k2<128 -> Wiou[k2][j],   else Uiou[k2-128][j]
//   col j>=384 : k2<128 -> Wf[k2][j-384], else Uf[k2-128][j-384]
// ---------------------------------------------------------------------------
__global__ void cvt_emb(const float* __restrict__ src, unsigned short* __restrict__ dst, int n4) {
    int i = blockIdx.x * 256 + threadIdx.x;
    if (i < n4) {
        float4 v = ((const float4*)src)[i];
        ushort4 o; o.x = f2bf(v.x); o.y = f2bf(v.y); o.z = f2bf(v.z); o.w = f2bf(v.w);
        ((ushort4*)dst)[i] = o;
    }
}

__global__ void build_bpack(const float* __restrict__ Wiou, const float* __restrict__ Uiou,
                            const float* __restrict__ Wf, const float* __restrict__ Uf,
                            unsigned short* __restrict__ pack) {
    int idx = blockIdx.x * 256 + threadIdx.x;      // 131072 total
    int c = idx >> 14, r = idx & 16383, j = r >> 5, kl = r & 31;
    int k2 = c * 32 + kl;
    float v;
    if (j < 384) v = (k2 < 128) ? Wiou[k2 * 384 + j] : Uiou[(k2 - 128) * 384 + j];
    else { int jf = j - 384; v = (k2 < 128) ? Wf[k2 * 128 + jf] : Uf[(k2 - 128) * 128 + jf]; }
    pack[idx] = f2bf(v);
}

// ---------------------------------------------------------------------------
// MFMA level kernel: 32 nodes/block, 256 threads (4 waves), levels d >= 5.
// A_s fragment-major layout (16B-aligned, conflict-free):
//   elem (region r, node m, k) at r*4096 + ((k>>5)*4 + ((k>>3)&3))*256 + m*8 + (k&7)
//   regions: 0=emb, 1=h_sum (computed in-LDS), 2=h_l, 3=h_r.  32 KB total.
// B fragments read DIRECTLY from global bpack (L2-resident; each element used
// by exactly one lane per block -> LDS staging would be pure overhead).
// Wave w owns output h-cols w*32..w*32+31 for all 5 gates -> lane-local epilogue.
// K-loop: chunks 0-3 emb (x_f shared, forked into accFr after), 4-7 h regions.
// No barriers inside the k-loop.
// ---------------------------------------------------------------------------
template<int HC>
__global__ __launch_bounds__(256, 2) void tree_level_mfma(
    const int* __restrict__ xids, const int* __restrict__ msk,
    const unsigned short* __restrict__ embB, const unsigned short* __restrict__ bpack,
    const float* __restrict__ biou, const float* __restrict__ bfv,
    const float* __restrict__ Wout, const float* __restrict__ bout,
    unsigned short* __restrict__ hB, float* __restrict__ c_ws, float* __restrict__ outp,
    int s0)
{
    __shared__ __align__(16) unsigned short A_s[16384];   // 32 KB
    __shared__ __align__(16) float wout_s[640];

    const int t  = threadIdx.x;
    const int g0 = s0 + blockIdx.x * 32;

    if (t < 160) ((float4*)wout_s)[t] = ((const float4*)Wout)[t];

    {   // ---- stage emb (region 0) ----
        const int n = t >> 3, seg = t & 7;
        const int g = g0 + n;
        const int ei = xids[g] * msk[g];
        const uint4* es = (const uint4*)(embB + (size_t)ei * 128 + seg * 16);
        uint4 e0 = es[0], e1 = es[1];
        const int cc = seg >> 1, q0 = (seg & 1) * 2;
        *(uint4*)&A_s[(cc * 4 + q0) * 256 + n * 8]       = e0;
        *(uint4*)&A_s[(cc * 4 + q0 + 1) * 256 + n * 8]   = e1;
        if (HC) {    // ---- stage h_l / h_r (regions 2,3) ----
            const int row = t >> 2, qt = t & 3;
            const int child = 2 * g0 + 1 + row;
            const int m = row >> 1, reg = 2 + (row & 1);
            const uint4* hp = (const uint4*)(hB + (size_t)child * 128 + qt * 32);
            uint4 p0 = hp[0], p1 = hp[1], p2 = hp[2], p3 = hp[3];
            unsigned short* base = &A_s[reg * 4096 + qt * 1024 + m * 8];
            *(uint4*)(base)       = p0;
            *(uint4*)(base + 256) = p1;
            *(uint4*)(base + 512) = p2;
            *(uint4*)(base + 768) = p3;
        }
    }
    if (HC) {        // ---- h_sum = h_l + h_r (region 1), in-LDS ----
        __syncthreads();
        const int m = t >> 3, seg = t & 7;
        const int cc = seg >> 1, q0 = (seg & 1) * 2;
        #pragma unroll
        for (int u = 0; u < 2; ++u) {
            const int idx = (cc * 4 + q0 + u) * 256 + m * 8;
            short8 l = *(short8*)&A_s[2 * 4096 + idx];
            short8 r = *(short8*)&A_s[3 * 4096 + idx];
            short8 s;
            #pragma unroll
            for (int j = 0; j < 8; ++j)
                s[j] = (short)f2bf(bf2f((unsigned short)l[j]) + bf2f((unsigned short)r[j]));
            *(short8*)&A_s[4096 + idx] = s;
        }
    }
    __syncthreads();

    const int lane = t & 63, w = t >> 6;
    const int ln = lane & 15, q = lane >> 4;

    // fragment base pointers (lane-linear)
    const unsigned short* bp = bpack + ln * 32 + q * 8;     // + c*16384 + tile*512
    const unsigned short* ap = A_s + q * 256 + ln * 8;      // + r*4096 + cc*1024 + rt*128

#define BF(c, tile) (*(const short8*)(bp + (c) * 16384 + (tile) * 512))
#define AF(r, cc, rt) (*(const short8*)(ap + (r) * 4096 + (cc) * 1024 + (rt) * 128))

    f32x4 accI[2][2] = {}, accO[2][2] = {}, accU[2][2] = {}, accFl[2][2] = {}, accFr[2][2] = {};
    const int ti = 2 * w, to = 8 + 2 * w, tu = 16 + 2 * w, tf = 24 + 2 * w;

    #pragma unroll
    for (int c = 0; c < 4; ++c) {      // emb chunks
        short8 bI0 = BF(c, ti), bI1 = BF(c, ti + 1);
        short8 bO0 = BF(c, to), bO1 = BF(c, to + 1);
        short8 bU0 = BF(c, tu), bU1 = BF(c, tu + 1);
        short8 aE0 = AF(0, c, 0), aE1 = AF(0, c, 1);
        accI[0][0] = __builtin_amdgcn_mfma_f32_16x16x32_bf16(aE0, bI0, accI[0][0], 0, 0, 0);
        accI[0][1] = __builtin_amdgcn_mfma_f32_16x16x32_bf16(aE0, bI1, accI[0][1], 0, 0, 0);
        accI[1][0] = __builtin_amdgcn_mfma_f32_16x16x32_bf16(aE1, bI0, accI[1][0], 0, 0, 0);
        accI[1][1] = __builtin_amdgcn_mfma_f32_16x16x32_bf16(aE1, bI1, accI[1][1], 0, 0, 0);
        accO[0][0] = __builtin_amdgcn_mfma_f32_16x16x32_bf16(aE0, bO0, accO[0][0], 0, 0, 0);
        accO[0][1] = __builtin_amdgcn_mfma_f32_16x16x32_bf16(aE0, bO1, accO[0][1], 0, 0, 0);
        accO[1][0] = __builtin_amdgcn_mfma_f32_16x16x32_bf16(aE1, bO0, accO[1][0], 0, 0, 0);
        accO[1][1] = __builtin_amdgcn_mfma_f32_16x16x32_bf16(aE1, bO1, accO[1][1], 0, 0, 0);
        accU[0][0] = __builtin_amdgcn_mfma_f32_16x16x32_bf16(aE0, bU0, accU[0][0], 0, 0, 0);
        accU[0][1] = __builtin_amdgcn_mfma_f32_16x16x32_bf16(aE0, bU1, accU[0][1], 0, 0, 0);
        accU[1][0] = __builtin_amdgcn_mfma_f32_16x16x32_bf16(aE1, bU0, accU[1][0], 0, 0, 0);
        accU[1][1] = __builtin_amdgcn_mfma_f32_16x16x32_bf16(aE1, bU1, accU[1][1], 0, 0, 0);
        if (HC) {
            short8 bF0 = BF(c, tf), bF1 = BF(c, tf + 1);
            accFl[0][0] = __builtin_amdgcn_mfma_f32_16x16x32_bf16(aE0, bF0, accFl[0][0], 0, 0, 0);
            accFl[0][1] = __builtin_amdgcn_mfma_f32_16x16x32_bf16(aE0, bF1, accFl[0][1], 0, 0, 0);
            accFl[1][0] = __builtin_amdgcn_mfma_f32_16x16x32_bf16(aE1, bF0, accFl[1][0], 0, 0, 0);
            accFl[1][1] = __builtin_amdgcn_mfma_f32_16x16x32_bf16(aE1, bF1, accFl[1][1], 0, 0, 0);
        }
    }
    if (HC) {
        #pragma unroll
        for (int rt = 0; rt < 2; ++rt)
            #pragma unroll
            for (int jt = 0; jt < 2; ++jt)
                accFr[rt][jt] = accFl[rt][jt];      // fork shared x_f
        #pragma unroll
        for (int c = 0; c < 4; ++c) {  // h chunks (global chunk 4+c)
            short8 bI0 = BF(4 + c, ti), bI1 = BF(4 + c, ti + 1);
            short8 bO0 = BF(4 + c, to), bO1 = BF(4 + c, to + 1);
            short8 bU0 = BF(4 + c, tu), bU1 = BF(4 + c, tu + 1);
            short8 bF0 = BF(4 + c, tf), bF1 = BF(4 + c, tf + 1);
            short8 aH0 = AF(1, c, 0), aH1 = AF(1, c, 1);
            short8 aL0 = AF(2, c, 0), aL1 = AF(2, c, 1);
            short8 aR0 = AF(3, c, 0), aR1 = AF(3, c, 1);
            accI[0][0] = __builtin_amdgcn_mfma_f32_16x16x32_bf16(aH0, bI0, accI[0][0], 0, 0, 0);
            accI[0][1] = __builtin_amdgcn_mfma_f32_16x16x32_bf16(aH0, bI1, accI[0][1], 0, 0, 0);
            accI[1][0] = __builtin_amdgcn_mfma_f32_16x16x32_bf16(aH1, bI0, accI[1][0], 0, 0, 0);
            accI[1][1] = __builtin_amdgcn_mfma_f32_16x16x32_bf16(aH1, bI1, accI[1][1], 0, 0, 0);
            accO[0][0] = __builtin_amdgcn_mfma_f32_16x16x32_bf16(aH0, bO0, accO[0][0], 0, 0, 0);
            accO[0][1] = __builtin_amdgcn_mfma_f32_16x16x32_bf16(aH0, bO1, accO[0][1], 0, 0, 0);
            accO[1][0] = __builtin_amdgcn_mfma_f32_16x16x32_bf16(aH1, bO0, accO[1][0], 0, 0, 0);
            accO[1][1] = __builtin_amdgcn_mfma_f32_16x16x32_bf16(aH1, bO1, accO[1][1], 0, 0, 0);
            accU[0][0] = __builtin_amdgcn_mfma_f32_16x16x32_bf16(aH0, bU0, accU[0][0], 0, 0, 0);
            accU[0][1] = __builtin_amdgcn_mfma_f32_16x16x32_bf16(aH0, bU1, accU[0][1], 0, 0, 0);
            accU[1][0] = __builtin_amdgcn_mfma_f32_16x16x32_bf16(aH1, bU0, accU[1][0], 0, 0, 0);
            accU[1][1] = __builtin_amdgcn_mfma_f32_16x16x32_bf16(aH1, bU1, accU[1][1], 0, 0, 0);
            accFl[0][0] = __builtin_amdgcn_mfma_f32_16x16x32_bf16(aL0, bF0, accFl[0][0], 0, 0, 0);
            accFl[0][1] = __builtin_amdgcn_mfma_f32_16x16x32_bf16(aL0, bF1, accFl[0][1], 0, 0, 0);
            accFl[1][0] = __builtin_amdgcn_mfma_f32_16x16x32_bf16(aL1, bF0, accFl[1][0], 0, 0, 0);
            accFl[1][1] = __builtin_amdgcn_mfma_f32_16x16x32_bf16(aL1, bF1, accFl[1][1], 0, 0, 0);
            accFr[0][0] = __builtin_amdgcn_mfma_f32_16x16x32_bf16(aR0, bF0, accFr[0][0], 0, 0, 0);
            accFr[0][1] = __builtin_amdgcn_mfma_f32_16x16x32_bf16(aR0, bF1, accFr[0][1], 0, 0, 0);
            accFr[1][0] = __builtin_amdgcn_mfma_f32_16x16x32_bf16(aR1, bF0, accFr[1][0], 0, 0, 0);
            accFr[1][1] = __builtin_amdgcn_mfma_f32_16x16x32_bf16(aR1, bF1, accFr[1][1], 0, 0, 0);
        }
    }
#undef BF
#undef AF

    __syncthreads();                 // all A_s reads done; reuse as f32 h_s
    float* h_s = (float*)A_s;        // 32 x 132 f32 (16.9 KB <= 32 KB)

    #pragma unroll
    for (int rt = 0; rt < 2; ++rt) {
        #pragma unroll
        for (int jt = 0; jt < 2; ++jt) {
            const int col = w * 32 + jt * 16 + ln;
            const float bib = biou[col], bob = biou[128 + col], bub = biou[256 + col];
            const float bfb = bfv[col];
            #pragma unroll
            for (int r = 0; r < 4; ++r) {
                const int row = rt * 16 + q * 4 + r;
                const int g = g0 + row;
                const float iv = accI[rt][jt][r] + bib;
                const float ov = accO[rt][jt][r] + bob;
                const float uv = accU[rt][jt][r] + bub;
                float fc = 0.f;
                if (HC) {
                    const float cl = c_ws[(size_t)(2 * g + 1) * 128 + col];
                    const float cr = c_ws[(size_t)(2 * g + 2) * 128 + col];
                    const float fl = sigm_(accFl[rt][jt][r] + bfb);
                    const float fr = sigm_(accFr[rt][jt][r] + bfb);
                    fc = fl * cl + fr * cr;
                }
                const float cc = sigm_(iv) * tanh_(uv) + fc;
                const float hh = sigm_(ov) * tanh_(cc);
                c_ws[(size_t)g * 128 + col] = cc;
                hB[(size_t)g * 128 + col] = f2bf(hh);
                h_s[row * 132 + col] = hh;
            }
        }
    }
    __syncthreads();
    if (t < 160) {                   // output head: 32 nodes x 5 cols, f32
        const int n = t / 5, cc5 = t - 5 * n;
        float acc = bout[cc5];
        #pragma unroll 8
        for (int k = 0; k < 128; ++k) acc += h_s[n * 132 + k] * wout_s[k * 5 + cc5];
        outp[(size_t)(g0 + n) * 5 + cc5] = acc;
    }
}

// ---------------------------------------------------------------------------
// Small-level kernel (d <= 4): one block per node, f32 math.
// ---------------------------------------------------------------------------
__global__ __launch_bounds__(256) void tree_level_small(
    const int* __restrict__ xids, const int* __restrict__ msk,
    const unsigned short* __restrict__ embB,
    const float* __restrict__ Wiou, const float* __restrict__ Uiou, const float* __restrict__ biou,
    const float* __restrict__ Wf,   const float* __restrict__ Uf,   const float* __restrict__ bfv,
    const float* __restrict__ Wout, const float* __restrict__ bout,
    unsigned short* __restrict__ hB, float* __restrict__ c_ws, float* __restrict__ outp,
    int s0)
{
    __shared__ __align__(16) float emb_s[128], hs_s[128], hl_s[128], hr_s[128];
    __shared__ __align__(16) float cl_s[128], cr_s[128];
    __shared__ __align__(16) float O_s[640];

    const int g  = s0 + blockIdx.x;
    const int t  = threadIdx.x;
    const int ei = xids[g] * msk[g];
    const int gl = 2 * g + 1, gr = 2 * g + 2;

    if (t < 16) {
        uint4 raw = ((const uint4*)(embB + (size_t)ei * 128))[t];
        const unsigned short* p = (const unsigned short*)&raw;
        #pragma unroll
        for (int j = 0; j < 8; ++j) emb_s[t * 8 + j] = bf2f(p[j]);
    } else if (t < 32) {
        uint4 raw = ((const uint4*)(hB + (size_t)gl * 128))[t - 16];
        const unsigned short* p = (const unsigned short*)&raw;
        #pragma unroll
        for (int j = 0; j < 8; ++j) hl_s[(t - 16) * 8 + j] = bf2f(p[j]);
    } else if (t < 48) {
        uint4 raw = ((const uint4*)(hB + (size_t)gr * 128))[t - 32];
        const unsigned short* p = (const unsigned short*)&raw;
        #pragma unroll
        for (int j = 0; j < 8; ++j) hr_s[(t - 32) * 8 + j] = bf2f(p[j]);
    } else if (t < 80) {
        ((float4*)cl_s)[t - 48] = ((const float4*)(c_ws + (size_t)gl * 128))[t - 48];
    } else if (t < 112) {
        ((float4*)cr_s)[t - 80] = ((const float4*)(c_ws + (size_t)gr * 128))[t - 80];
    }
    __syncthreads();
    if (t < 128) hs_s[t] = hl_s[t] + hr_s[t];
    __syncthreads();

    const int c0 = t;
    const int c1 = 256 + t;
    const float* B10 = Wiou + c0;
    const float* B20 = Uiou + c0;
    const float *B11, *B21, *A21;
    int st1;
    if (c1 < 384) { B11 = Wiou + c1;        B21 = Uiou + c1;        st1 = 384; A21 = hs_s; }
    else          { B11 = Wf + (c1 - 384);  B21 = Uf + (c1 - 384);  st1 = 128; A21 = hl_s; }
    const int c2c = (t < 128) ? t : 0;
    const float* B12 = Wf + c2c;
    const float* B22 = Uf + c2c;

    float a0 = 0.f, a1 = 0.f, a2 = 0.f;
    #pragma unroll 4
    for (int k = 0; k < 128; ++k) {
        const float e = emb_s[k];
        a0 += e * B10[k * 384];
        a0 += hs_s[k] * B20[k * 384];
        a1 += e * B11[k * st1];
        a1 += A21[k] * B21[k * st1];
        a2 += e * B12[k * 128];
        a2 += hr_s[k] * B22[k * 128];
    }
    O_s[c0] = a0;
    O_s[c1] = a1;
    if (t < 128) O_s[512 + t] = a2;
    __syncthreads();

    if (t < 128) {
        const int k = t;
        const float ii = O_s[k]       + biou[k];
        const float oo = O_s[128 + k] + biou[128 + k];
        const float uu = O_s[256 + k] + biou[256 + k];
        const float fl = sigm_(O_s[384 + k] + bfv[k]);
        const float fr = sigm_(O_s[512 + k] + bfv[k]);
        const float fc = fl * cl_s[k] + fr * cr_s[k];
        const float cc = sigm_(ii) * tanh_(uu) + fc;
        const float hh = sigm_(oo) * tanh_(cc);
        c_ws[(size_t)g * 128 + k] = cc;
        hB[(size_t)g * 128 + k] = f2bf(hh);
        O_s[k] = hh;
    }
    __syncthreads();
    if (t < 5) {
        float acc = bout[t];
        for (int k = 0; k < 128; ++k) acc += O_s[k] * Wout[k * 5 + t];
        outp[(size_t)g * 5 + t] = acc;
    }
}

extern "C" void kernel_launch(void* const* d_in, const int* in_sizes, int n_in,
                              void* d_out, int out_size, void* d_ws, size_t ws_size,
                              hipStream_t stream)
{
    (void)in_sizes; (void)n_in; (void)out_size; (void)ws_size;
    const int*   xids = (const int*)d_in[0];
    const int*   msk  = (const int*)d_in[1];
    const float* emb  = (const float*)d_in[2];
    const float* Wiou = (const float*)d_in[3];
    const float* Uiou = (const float*)d_in[4];
    const float* biou = (const float*)d_in[5];
    const float* Wf   = (const float*)d_in[6];
    const float* Uf   = (const float*)d_in[7];
    const float* bfv  = (const float*)d_in[8];
    const float* Wout = (const float*)d_in[9];
    const float* bout = (const float*)d_in[10];
    float* outp = (float*)d_out;

    // workspace: embB (8.2MB) | bpack (0.26MB) | hB (67MB) | c_ws f32 (134MB)
    unsigned short* embB  = (unsigned short*)d_ws;
    unsigned short* bpack = embB + (size_t)32000 * 128;
    unsigned short* hB    = bpack + 131072;
    float*          c_ws  = (float*)(hB + (size_t)NN * 128);

    cvt_emb<<<dim3((32000 * 128 / 4 + 255) / 256), dim3(256), 0, stream>>>(emb, embB, 32000 * 128 / 4);
    build_bpack<<<dim3(131072 / 256), dim3(256), 0, stream>>>(Wiou, Uiou, Wf, Uf, bpack);

    {   // leaf level d = 17
        const int d = DEPTH - 1, s0 = (1 << d) - 1;
        tree_level_mfma<0><<<dim3((1 << d) / 32), dim3(256), 0, stream>>>(
            xids, msk, embB, bpack, biou, bfv, Wout, bout, hB, c_ws, outp, s0);
    }
    for (int d = DEPTH - 2; d >= 5; --d) {
        const int s0 = (1 << d) - 1;
        tree_level_mfma<1><<<dim3((1 << d) / 32), dim3(256), 0, stream>>>(
            xids, msk, embB, bpack, biou, bfv, Wout, bout, hB, c_ws, outp, s0);
    }
    for (int d = 4; d >= 0; --d) {
        const int s0 = (1 << d) - 1;
        tree_level_small<<<dim3(1 << d), dim3(256), 0, stream>>>(
            xids, msk, embB, Wiou, Uiou, biou, Wf, Uf, bfv, Wout, bout,
            hB, c_ws, outp, s0);
    }
}

// Round 4
// 447.154 us; speedup vs baseline: 3.5707x; 1.1846x over previous
//
#include <hip/hip_runtime.h>

#define DEPTH 18
#define NN ((1 << DEPTH) - 1)   // 262143

typedef __attribute__((ext_vector_type(8))) short short8;
typedef __attribute__((ext_vector_type(4))) float f32x4;

__device__ __forceinline__ float sigm_(float x) { return 1.f / (1.f + __expf(-x)); }
__device__ __forceinline__ float tanh_(float x) { float e = __expf(2.f * x); return 1.f - 2.f / (e + 1.f); }
__device__ __forceinline__ unsigned short f2bf(float f) {
    union { float f; unsigned int u; } v; v.f = f;
    unsigned int r = (v.u + 0x7fffu + ((v.u >> 16) & 1u)) >> 16;
    return (unsigned short)r;
}
__device__ __forceinline__ float bf2f(unsigned short h) {
    union { unsigned int u; float f; } v; v.u = ((unsigned int)h) << 16; return v.f;
}

// ---------------------------------------------------------------------------
// Prep: emb table -> bf16; packed bf16 B matrix.
// bpack layout: [chunk c (8)][col j (512)][k-local (32)], contiguous bf16.
//   chunks 0-3 (x side):  col j<384: Wiou[k][j], j>=384: Wf[k][j-384]
//   chunks 4-7 (h side):  col j<384: Uiou[k][j], j>=384: Uf[k][j-384]
// ---------------------------------------------------------------------------
__global__ void cvt_emb(const float* __restrict__ src, unsigned short* __restrict__ dst, int n4) {
    int i = blockIdx.x * 256 + threadIdx.x;
    if (i < n4) {
        float4 v = ((const float4*)src)[i];
        ushort4 o; o.x = f2bf(v.x); o.y = f2bf(v.y); o.z = f2bf(v.z); o.w = f2bf(v.w);
        ((ushort4*)dst)[i] = o;
    }
}

__global__ void build_bpack(const float* __restrict__ Wiou, const float* __restrict__ Uiou,
                            const float* __restrict__ Wf, const float* __restrict__ Uf,
                            unsigned short* __restrict__ pack) {
    int idx = blockIdx.x * 256 + threadIdx.x;      // 131072 total
    int c = idx >> 14, r = idx & 16383, j = r >> 5, kl = r & 31;
    int k2 = c * 32 + kl;                          // 0..255; <128 = x side
    float v;
    if (j < 384) v = (k2 < 128) ? Wiou[k2 * 384 + j] : Uiou[(k2 - 128) * 384 + j];
    else { int jf = j - 384; v = (k2 < 128) ? Wf[k2 * 128 + jf] : Uf[(k2 - 128) * 128 + jf]; }
    pack[idx] = f2bf(v);
}

// ---------------------------------------------------------------------------
// Big-level MFMA kernel: 32 nodes/block, 256 threads (4 waves), d >= 10.
// A_s regions: 0=emb, 1=h_l, 2=h_r (NO h_sum — hl/hr feed iou accumulators
// via separate MFMAs, trading idle MFMA pipe for busy VALU).
// A elem (region r, node m, k) at r*4096 + ((k>>5)*4 + ((k>>3)&3))*256 + m*8 + (k&7)
// B fragments read directly from global bpack (L2-resident, zero reuse/blk).
// Wave w owns output cols w*32..+31 for all 5 gates -> lane-local epilogue.
// ---------------------------------------------------------------------------
template<int HC>
__global__ __launch_bounds__(256, 2) void tree_level_mfma(
    const int* __restrict__ xids, const int* __restrict__ msk,
    const unsigned short* __restrict__ embB, const unsigned short* __restrict__ bpack,
    const float* __restrict__ biou, const float* __restrict__ bfv,
    const float* __restrict__ Wout, const float* __restrict__ bout,
    unsigned short* __restrict__ hB, float* __restrict__ c_ws, float* __restrict__ outp,
    int s0)
{
    __shared__ __align__(16) unsigned short A_s[12288];   // 3 x 4096, 24 KB
    __shared__ __align__(16) float wout_s[640];

    const int t  = threadIdx.x;
    const int g0 = s0 + blockIdx.x * 32;

    if (t < 160) ((float4*)wout_s)[t] = ((const float4*)Wout)[t];

    {   // ---- stage emb (region 0) ----
        const int n = t >> 3, seg = t & 7;
        const int g = g0 + n;
        const int ei = xids[g] * msk[g];
        const uint4* es = (const uint4*)(embB + (size_t)ei * 128 + seg * 16);
        uint4 e0 = es[0], e1 = es[1];
        const int cc = seg >> 1, q0 = (seg & 1) * 2;
        *(uint4*)&A_s[(cc * 4 + q0) * 256 + n * 8]       = e0;
        *(uint4*)&A_s[(cc * 4 + q0 + 1) * 256 + n * 8]   = e1;
        if (HC) {    // ---- stage h_l / h_r (regions 1,2) ----
            const int row = t >> 2, qt = t & 3;
            const int child = 2 * g0 + 1 + row;
            const int m = row >> 1, reg = 1 + (row & 1);
            const uint4* hp = (const uint4*)(hB + (size_t)child * 128 + qt * 32);
            uint4 p0 = hp[0], p1 = hp[1], p2 = hp[2], p3 = hp[3];
            unsigned short* base = &A_s[reg * 4096 + qt * 1024 + m * 8];
            *(uint4*)(base)       = p0;
            *(uint4*)(base + 256) = p1;
            *(uint4*)(base + 512) = p2;
            *(uint4*)(base + 768) = p3;
        }
    }
    __syncthreads();

    const int lane = t & 63, w = t >> 6;
    const int ln = lane & 15, q = lane >> 4;

    const unsigned short* bp = bpack + ln * 32 + q * 8;     // + c*16384 + tile*512
    const unsigned short* ap = A_s + q * 256 + ln * 8;      // + r*4096 + cc*1024 + rt*128

#define BF(c, tile) (*(const short8*)(bp + (c) * 16384 + (tile) * 512))
#define AF(r, cc, rt) (*(const short8*)(ap + (r) * 4096 + (cc) * 1024 + (rt) * 128))
#define MM(acc, a, b) acc = __builtin_amdgcn_mfma_f32_16x16x32_bf16(a, b, acc, 0, 0, 0)

    f32x4 accI[2][2] = {}, accO[2][2] = {}, accU[2][2] = {}, accFl[2][2] = {}, accFr[2][2] = {};
    const int ti = 2 * w, to = 8 + 2 * w, tu = 16 + 2 * w, tf = 24 + 2 * w;

    #pragma unroll
    for (int c = 0; c < 4; ++c) {      // emb chunks
        short8 bI0 = BF(c, ti), bI1 = BF(c, ti + 1);
        short8 bO0 = BF(c, to), bO1 = BF(c, to + 1);
        short8 bU0 = BF(c, tu), bU1 = BF(c, tu + 1);
        short8 aE0 = AF(0, c, 0), aE1 = AF(0, c, 1);
        MM(accI[0][0], aE0, bI0); MM(accI[0][1], aE0, bI1);
        MM(accI[1][0], aE1, bI0); MM(accI[1][1], aE1, bI1);
        MM(accO[0][0], aE0, bO0); MM(accO[0][1], aE0, bO1);
        MM(accO[1][0], aE1, bO0); MM(accO[1][1], aE1, bO1);
        MM(accU[0][0], aE0, bU0); MM(accU[0][1], aE0, bU1);
        MM(accU[1][0], aE1, bU0); MM(accU[1][1], aE1, bU1);
        if (HC) {
            short8 bF0 = BF(c, tf), bF1 = BF(c, tf + 1);
            MM(accFl[0][0], aE0, bF0); MM(accFl[0][1], aE0, bF1);
            MM(accFl[1][0], aE1, bF0); MM(accFl[1][1], aE1, bF1);
        }
    }
    if (HC) {
        #pragma unroll
        for (int rt = 0; rt < 2; ++rt)
            #pragma unroll
            for (int jt = 0; jt < 2; ++jt)
                accFr[rt][jt] = accFl[rt][jt];      // fork shared x_f
        #pragma unroll
        for (int c = 0; c < 4; ++c) {  // h chunks (bpack chunk 4+c)
            short8 bI0 = BF(4 + c, ti), bI1 = BF(4 + c, ti + 1);
            short8 bO0 = BF(4 + c, to), bO1 = BF(4 + c, to + 1);
            short8 bU0 = BF(4 + c, tu), bU1 = BF(4 + c, tu + 1);
            short8 bF0 = BF(4 + c, tf), bF1 = BF(4 + c, tf + 1);
            short8 aL0 = AF(1, c, 0), aL1 = AF(1, c, 1);
            short8 aR0 = AF(2, c, 0), aR1 = AF(2, c, 1);
            MM(accI[0][0], aL0, bI0); MM(accI[0][0], aR0, bI0);
            MM(accI[0][1], aL0, bI1); MM(accI[0][1], aR0, bI1);
            MM(accI[1][0], aL1, bI0); MM(accI[1][0], aR1, bI0);
            MM(accI[1][1], aL1, bI1); MM(accI[1][1], aR1, bI1);
            MM(accO[0][0], aL0, bO0); MM(accO[0][0], aR0, bO0);
            MM(accO[0][1], aL0, bO1); MM(accO[0][1], aR0, bO1);
            MM(accO[1][0], aL1, bO0); MM(accO[1][0], aR1, bO0);
            MM(accO[1][1], aL1, bO1); MM(accO[1][1], aR1, bO1);
            MM(accU[0][0], aL0, bU0); MM(accU[0][0], aR0, bU0);
            MM(accU[0][1], aL0, bU1); MM(accU[0][1], aR0, bU1);
            MM(accU[1][0], aL1, bU0); MM(accU[1][0], aR1, bU0);
            MM(accU[1][1], aL1, bU1); MM(accU[1][1], aR1, bU1);
            MM(accFl[0][0], aL0, bF0); MM(accFl[0][1], aL0, bF1);
            MM(accFl[1][0], aL1, bF0); MM(accFl[1][1], aL1, bF1);
            MM(accFr[0][0], aR0, bF0); MM(accFr[0][1], aR0, bF1);
            MM(accFr[1][0], aR1, bF0); MM(accFr[1][1], aR1, bF1);
        }
    }
#undef BF
#undef AF

    __syncthreads();                 // all A_s reads done; reuse as f32 h_s
    float* h_s = (float*)A_s;        // 32 x 132 f32 (16.9 KB <= 24 KB)

    #pragma unroll
    for (int rt = 0; rt < 2; ++rt) {
        #pragma unroll
        for (int jt = 0; jt < 2; ++jt) {
            const int col = w * 32 + jt * 16 + ln;
            const float bib = biou[col], bob = biou[128 + col], bub = biou[256 + col];
            const float bfb = bfv[col];
            #pragma unroll
            for (int r = 0; r < 4; ++r) {
                const int row = rt * 16 + q * 4 + r;
                const int g = g0 + row;
                const float iv = accI[rt][jt][r] + bib;
                const float ov = accO[rt][jt][r] + bob;
                const float uv = accU[rt][jt][r] + bub;
                float fc = 0.f;
                if (HC) {
                    const float cl = c_ws[(size_t)(2 * g + 1) * 128 + col];
                    const float cr = c_ws[(size_t)(2 * g + 2) * 128 + col];
                    const float fl = sigm_(accFl[rt][jt][r] + bfb);
                    const float fr = sigm_(accFr[rt][jt][r] + bfb);
                    fc = fl * cl + fr * cr;
                }
                const float cc = sigm_(iv) * tanh_(uv) + fc;
                const float hh = sigm_(ov) * tanh_(cc);
                c_ws[(size_t)g * 128 + col] = cc;
                hB[(size_t)g * 128 + col] = f2bf(hh);
                h_s[row * 132 + col] = hh;
            }
        }
    }
    __syncthreads();
    if (t < 160) {                   // output head: 32 nodes x 5 cols, f32
        const int n = t / 5, cc5 = t - 5 * n;
        float acc = bout[cc5];
        #pragma unroll 8
        for (int k = 0; k < 128; ++k) acc += h_s[n * 132 + k] * wout_s[k * 5 + cc5];
        outp[(size_t)(g0 + n) * 5 + cc5] = acc;
    }
}

// ---------------------------------------------------------------------------
// Subtree kernel: block b processes levels d = dTop..dBot for the subtree
// whose dBot-level root is node (2^dBot-1)+b.  dTop-dBot == 4 (16..1 nodes).
// 16-row MFMA tiles (rt=1); h carried between mini-levels in A_s fragment
// layout; c carried in double-buffered LDS.  All levels here have children.
// A elem (region r, m, k) at r*2048 + (k>>5)*512 + (((k>>3)&3)*16 + m)*8 + (k&7)
// ---------------------------------------------------------------------------
__global__ __launch_bounds__(256) void tree_subtree(
    const int* __restrict__ xids, const int* __restrict__ msk,
    const unsigned short* __restrict__ embB, const unsigned short* __restrict__ bpack,
    const float* __restrict__ biou, const float* __restrict__ bfv,
    const float* __restrict__ Wout, const float* __restrict__ bout,
    unsigned short* __restrict__ hB, float* __restrict__ c_ws, float* __restrict__ outp,
    int dTop, int dBot)
{
    __shared__ __align__(16) unsigned short A_s[6144];    // 3 x 2048, 12 KB
    __shared__ __align__(16) float cbuf[2][16][128];      // 16 KB
    __shared__ __align__(16) float wout_s[640];

    const int t = threadIdx.x, b = blockIdx.x;
    const int lane = t & 63, w = t >> 6;
    const int ln = lane & 15, q = lane >> 4;

    if (t < 160) ((float4*)wout_s)[t] = ((const float4*)Wout)[t];

    // per-lane epilogue constants (col fixed across levels)
    const int col0 = w * 32 + ln, col1 = col0 + 16;
    const float bib0 = biou[col0], bob0 = biou[128 + col0], bub0 = biou[256 + col0], bfb0 = bfv[col0];
    const float bib1 = biou[col1], bob1 = biou[128 + col1], bub1 = biou[256 + col1], bfb1 = bfv[col1];

    const unsigned short* bp = bpack + ln * 32 + q * 8;
    const unsigned short* ap = A_s + (q * 16 + ln) * 8;
    const int ti = 2 * w, to = 8 + 2 * w, tu = 16 + 2 * w, tf = 24 + 2 * w;

    for (int d = dTop; d >= dBot; --d) {
        const int nd = 1 << (d - dBot);
        const int g0 = ((1 << d) - 1) + (b << (d - dBot));
        const int par = (dTop - d) & 1;

        if (t < 128) {   // stage emb (region 0), 16 rows (garbage rows >= nd ok)
            const int m = t >> 3, seg = t & 7;
            const int g = g0 + m;
            const int ei = xids[g] * msk[g];
            const uint4* es = (const uint4*)(embB + (size_t)ei * 128 + seg * 16);
            uint4 e0 = es[0], e1 = es[1];
            const int cc = seg >> 1, q0 = (seg & 1) * 2;
            *(uint4*)&A_s[cc * 512 + (q0 * 16 + m) * 8]       = e0;
            *(uint4*)&A_s[cc * 512 + ((q0 + 1) * 16 + m) * 8] = e1;
        }
        if (d == dTop) {   // stage 32 child h rows from global
            const int row = t >> 3, sg = t & 7;
            const int child = 2 * g0 + 1 + row;
            const uint4* hp = (const uint4*)(hB + (size_t)child * 128 + sg * 16);
            uint4 h0 = hp[0], h1 = hp[1];
            const int reg = 1 + (row & 1), mm = row >> 1;
            const int cc = sg >> 1, q0 = (sg & 1) * 2;
            *(uint4*)&A_s[reg * 2048 + cc * 512 + (q0 * 16 + mm) * 8]       = h0;
            *(uint4*)&A_s[reg * 2048 + cc * 512 + ((q0 + 1) * 16 + mm) * 8] = h1;
        }
        __syncthreads();

        f32x4 accI[2] = {}, accO[2] = {}, accU[2] = {}, accFl[2] = {}, accFr[2] = {};
#define BF1(c, tile) (*(const short8*)(bp + (c) * 16384 + (tile) * 512))
#define AF1(r, c) (*(const short8*)(ap + (r) * 2048 + (c) * 512))
        #pragma unroll
        for (int c = 0; c < 4; ++c) {
            short8 aE = AF1(0, c);
            MM(accI[0], aE, BF1(c, ti)); MM(accI[1], aE, BF1(c, ti + 1));
            MM(accO[0], aE, BF1(c, to)); MM(accO[1], aE, BF1(c, to + 1));
            MM(accU[0], aE, BF1(c, tu)); MM(accU[1], aE, BF1(c, tu + 1));
            MM(accFl[0], aE, BF1(c, tf)); MM(accFl[1], aE, BF1(c, tf + 1));
        }
        accFr[0] = accFl[0]; accFr[1] = accFl[1];
        #pragma unroll
        for (int c = 0; c < 4; ++c) {
            short8 aL = AF1(1, c), aR = AF1(2, c);
            short8 bI0 = BF1(4 + c, ti), bI1 = BF1(4 + c, ti + 1);
            short8 bO0 = BF1(4 + c, to), bO1 = BF1(4 + c, to + 1);
            short8 bU0 = BF1(4 + c, tu), bU1 = BF1(4 + c, tu + 1);
            short8 bF0 = BF1(4 + c, tf), bF1 = BF1(4 + c, tf + 1);
            MM(accI[0], aL, bI0); MM(accI[0], aR, bI0);
            MM(accI[1], aL, bI1); MM(accI[1], aR, bI1);
            MM(accO[0], aL, bO0); MM(accO[0], aR, bO0);
            MM(accO[1], aL, bO1); MM(accO[1], aR, bO1);
            MM(accU[0], aL, bU0); MM(accU[0], aR, bU0);
            MM(accU[1], aL, bU1); MM(accU[1], aR, bU1);
            MM(accFl[0], aL, bF0); MM(accFl[1], aL, bF1);
            MM(accFr[0], aR, bF0); MM(accFr[1], aR, bF1);
        }
#undef BF1
#undef AF1
        __syncthreads();   // k-loop reads done before epilogue overwrites A_s h

        #pragma unroll
        for (int jt = 0; jt < 2; ++jt) {
            const int col = jt ? col1 : col0;
            const float bib = jt ? bib1 : bib0, bob = jt ? bob1 : bob0;
            const float bub = jt ? bub1 : bub0, bfb = jt ? bfb1 : bfb0;
            const f32x4 aI = accI[jt], aO = accO[jt], aU = accU[jt];
            const f32x4 aFl = accFl[jt], aFr = accFr[jt];
            #pragma unroll
            for (int r = 0; r < 4; ++r) {
                const int row = q * 4 + r;
                const int g = g0 + row;
                float cl, cr;
                if (d == dTop) {
                    cl = c_ws[(size_t)(2 * g + 1) * 128 + col];
                    cr = c_ws[(size_t)(2 * g + 2) * 128 + col];
                } else {
                    cl = cbuf[1 - par][2 * row][col];
                    cr = cbuf[1 - par][2 * row + 1][col];
                }
                const float iv = aI[r] + bib;
                const float ov = aO[r] + bob;
                const float uv = aU[r] + bub;
                const float fl = sigm_(aFl[r] + bfb);
                const float fr = sigm_(aFr[r] + bfb);
                const float cc = sigm_(iv) * tanh_(uv) + fl * cl + fr * cr;
                const float hh = sigm_(ov) * tanh_(cc);
                cbuf[par][row][col] = cc;
                const unsigned short hb = f2bf(hh);
                // write h into A_s child layout for next (parent) level
                const int reg = 1 + (row & 1), mm = row >> 1;
                A_s[reg * 2048 + (col >> 5) * 512 + ((((col >> 3) & 3) * 16) + mm) * 8 + (col & 7)] = hb;
                if (row < nd) {
                    c_ws[(size_t)g * 128 + col] = cc;
                    hB[(size_t)g * 128 + col] = hb;
                }
            }
        }
        __syncthreads();
        if (t < nd * 5) {            // output head for this level's nodes
            const int n = t / 5, cc5 = t - 5 * n;
            const int reg = 1 + (n & 1), mm = n >> 1;
            float acc = bout[cc5];
            #pragma unroll 8
            for (int k = 0; k < 128; ++k) {
                const float hv = bf2f(A_s[reg * 2048 + (k >> 5) * 512 + ((((k >> 3) & 3) * 16) + mm) * 8 + (k & 7)]);
                acc += hv * wout_s[k * 5 + cc5];
            }
            outp[(size_t)(g0 + n) * 5 + cc5] = acc;
        }
        __syncthreads();
    }
}
#undef MM

extern "C" void kernel_launch(void* const* d_in, const int* in_sizes, int n_in,
                              void* d_out, int out_size, void* d_ws, size_t ws_size,
                              hipStream_t stream)
{
    (void)in_sizes; (void)n_in; (void)out_size; (void)ws_size;
    const int*   xids = (const int*)d_in[0];
    const int*   msk  = (const int*)d_in[1];
    const float* emb  = (const float*)d_in[2];
    const float* Wiou = (const float*)d_in[3];
    const float* Uiou = (const float*)d_in[4];
    const float* biou = (const float*)d_in[5];
    const float* Wf   = (const float*)d_in[6];
    const float* Uf   = (const float*)d_in[7];
    const float* bfv  = (const float*)d_in[8];
    const float* Wout = (const float*)d_in[9];
    const float* bout = (const float*)d_in[10];
    float* outp = (float*)d_out;

    // workspace: embB (8.2MB) | bpack (0.26MB) | hB (67MB) | c_ws f32 (134MB)
    unsigned short* embB  = (unsigned short*)d_ws;
    unsigned short* bpack = embB + (size_t)32000 * 128;
    unsigned short* hB    = bpack + 131072;
    float*          c_ws  = (float*)(hB + (size_t)NN * 128);

    cvt_emb<<<dim3((32000 * 128 / 4 + 255) / 256), dim3(256), 0, stream>>>(emb, embB, 32000 * 128 / 4);
    build_bpack<<<dim3(131072 / 256), dim3(256), 0, stream>>>(Wiou, Uiou, Wf, Uf, bpack);

    {   // leaf level d = 17
        const int d = DEPTH - 1, s0 = (1 << d) - 1;
        tree_level_mfma<0><<<dim3((1 << d) / 32), dim3(256), 0, stream>>>(
            xids, msk, embB, bpack, biou, bfv, Wout, bout, hB, c_ws, outp, s0);
    }
    for (int d = DEPTH - 2; d >= 10; --d) {
        const int s0 = (1 << d) - 1;
        tree_level_mfma<1><<<dim3((1 << d) / 32), dim3(256), 0, stream>>>(
            xids, msk, embB, bpack, biou, bfv, Wout, bout, hB, c_ws, outp, s0);
    }
    // levels 9..5: 32 subtree blocks; levels 4..0: 1 subtree block
    tree_subtree<<<dim3(32), dim3(256), 0, stream>>>(
        xids, msk, embB, bpack, biou, bfv, Wout, bout, hB, c_ws, outp, 9, 5);
    tree_subtree<<<dim3(1), dim3(256), 0, stream>>>(
        xids, msk, embB, bpack, biou, bfv, Wout, bout, hB, c_ws, outp, 4, 0);
}

// Round 5
// 399.435 us; speedup vs baseline: 3.9973x; 1.1195x over previous
//
#include <hip/hip_runtime.h>

#define DEPTH 18
#define NN ((1 << DEPTH) - 1)   // 262143

typedef __attribute__((ext_vector_type(8))) short short8;
typedef __attribute__((ext_vector_type(4))) float f32x4;

__device__ __forceinline__ float sigm_(float x) { return 1.f / (1.f + __expf(-x)); }
__device__ __forceinline__ float tanh_(float x) { float e = __expf(2.f * x); return 1.f - 2.f / (e + 1.f); }
__device__ __forceinline__ unsigned short f2bf(float f) {
    union { float f; unsigned int u; } v; v.f = f;
    unsigned int r = (v.u + 0x7fffu + ((v.u >> 16) & 1u)) >> 16;
    return (unsigned short)r;
}
__device__ __forceinline__ float bf2f(unsigned short h) {
    union { unsigned int u; float f; } v; v.u = ((unsigned int)h) << 16; return v.f;
}

// ---------------------------------------------------------------------------
// Prep: emb table -> bf16; packed bf16 B matrix.
// bpack layout: [chunk c (8)][col j (512)][k-local (32)], contiguous bf16.
//   chunks 0-3 (x side):  col j<384: Wiou[k][j], j>=384: Wf[k][j-384]
//   chunks 4-7 (h side):  col j<384: Uiou[k][j], j>=384: Uf[k][j-384]
// ---------------------------------------------------------------------------
__global__ void cvt_emb(const float* __restrict__ src, unsigned short* __restrict__ dst, int n4) {
    int i = blockIdx.x * 256 + threadIdx.x;
    if (i < n4) {
        float4 v = ((const float4*)src)[i];
        ushort4 o; o.x = f2bf(v.x); o.y = f2bf(v.y); o.z = f2bf(v.z); o.w = f2bf(v.w);
        ((ushort4*)dst)[i] = o;
    }
}

__global__ void build_bpack(const float* __restrict__ Wiou, const float* __restrict__ Uiou,
                            const float* __restrict__ Wf, const float* __restrict__ Uf,
                            unsigned short* __restrict__ pack) {
    int idx = blockIdx.x * 256 + threadIdx.x;      // 131072 total
    int c = idx >> 14, r = idx & 16383, j = r >> 5, kl = r & 31;
    int k2 = c * 32 + kl;                          // 0..255; <128 = x side
    float v;
    if (j < 384) v = (k2 < 128) ? Wiou[k2 * 384 + j] : Uiou[(k2 - 128) * 384 + j];
    else { int jf = j - 384; v = (k2 < 128) ? Wf[k2 * 128 + jf] : Uf[(k2 - 128) * 128 + jf]; }
    pack[idx] = f2bf(v);
}

// ---------------------------------------------------------------------------
// Big-level MFMA kernel: 32 nodes/block, 256 threads (4 waves), d >= 10.
// R3 structure (empirically faster than hl/hr-double-MFMA): A_s regions
// 0=emb, 1=h_sum (computed in-LDS), 2=h_l, 3=h_r; 20 MFMA/chunk k-loop.
// NEW (R5): cl/cr child-cell prefetch into registers BEFORE the k-loop, so
// the ~900-cyc LLC/HBM latency of the epilogue reads is hidden by the MFMAs.
// A elem (region r, node m, k) at r*4096 + ((k>>5)*4 + ((k>>3)&3))*256 + m*8 + (k&7)
// B fragments read directly from global bpack (L2-resident, zero reuse/blk).
// Wave w owns output cols w*32..+31 for all 5 gates -> lane-local epilogue.
// ---------------------------------------------------------------------------
template<int HC>
__global__ __launch_bounds__(256, 2) void tree_level_mfma(
    const int* __restrict__ xids, const int* __restrict__ msk,
    const unsigned short* __restrict__ embB, const unsigned short* __restrict__ bpack,
    const float* __restrict__ biou, const float* __restrict__ bfv,
    const float* __restrict__ Wout, const float* __restrict__ bout,
    unsigned short* __restrict__ hB, float* __restrict__ c_ws, float* __restrict__ outp,
    int s0)
{
    __shared__ __align__(16) unsigned short A_s[16384];   // 4 x 4096, 32 KB
    __shared__ __align__(16) float wout_s[640];

    const int t  = threadIdx.x;
    const int g0 = s0 + blockIdx.x * 32;

    if (t < 160) ((float4*)wout_s)[t] = ((const float4*)Wout)[t];

    {   // ---- stage emb (region 0) ----
        const int n = t >> 3, seg = t & 7;
        const int g = g0 + n;
        const int ei = xids[g] * msk[g];
        const uint4* es = (const uint4*)(embB + (size_t)ei * 128 + seg * 16);
        uint4 e0 = es[0], e1 = es[1];
        const int cc = seg >> 1, q0 = (seg & 1) * 2;
        *(uint4*)&A_s[(cc * 4 + q0) * 256 + n * 8]       = e0;
        *(uint4*)&A_s[(cc * 4 + q0 + 1) * 256 + n * 8]   = e1;
        if (HC) {    // ---- stage h_l / h_r (regions 2,3) ----
            const int row = t >> 2, qt = t & 3;
            const int child = 2 * g0 + 1 + row;
            const int m = row >> 1, reg = 2 + (row & 1);
            const uint4* hp = (const uint4*)(hB + (size_t)child * 128 + qt * 32);
            uint4 p0 = hp[0], p1 = hp[1], p2 = hp[2], p3 = hp[3];
            unsigned short* base = &A_s[reg * 4096 + qt * 1024 + m * 8];
            *(uint4*)(base)       = p0;
            *(uint4*)(base + 256) = p1;
            *(uint4*)(base + 512) = p2;
            *(uint4*)(base + 768) = p3;
        }
    }

    const int lane = t & 63, w = t >> 6;
    const int ln = lane & 15, q = lane >> 4;

    // ---- prefetch child c cells for the epilogue (fire-and-forget) ----
    float clp[2][2][4], crp[2][2][4];
    if (HC) {
        #pragma unroll
        for (int rt = 0; rt < 2; ++rt)
            #pragma unroll
            for (int jt = 0; jt < 2; ++jt) {
                const int col = w * 32 + jt * 16 + ln;
                #pragma unroll
                for (int r = 0; r < 4; ++r) {
                    const int g = g0 + rt * 16 + q * 4 + r;
                    clp[rt][jt][r] = c_ws[(size_t)(2 * g + 1) * 128 + col];
                    crp[rt][jt][r] = c_ws[(size_t)(2 * g + 2) * 128 + col];
                }
            }
    }

    if (HC) {        // ---- h_sum = h_l + h_r (region 1), in-LDS ----
        __syncthreads();
        const int m = t >> 3, seg = t & 7;
        const int cc = seg >> 1, q0 = (seg & 1) * 2;
        #pragma unroll
        for (int u = 0; u < 2; ++u) {
            const int idx = (cc * 4 + q0 + u) * 256 + m * 8;
            short8 l = *(short8*)&A_s[2 * 4096 + idx];
            short8 r = *(short8*)&A_s[3 * 4096 + idx];
            short8 s;
            #pragma unroll
            for (int j = 0; j < 8; ++j)
                s[j] = (short)f2bf(bf2f((unsigned short)l[j]) + bf2f((unsigned short)r[j]));
            *(short8*)&A_s[4096 + idx] = s;
        }
    }
    __syncthreads();

    const unsigned short* bp = bpack + ln * 32 + q * 8;     // + c*16384 + tile*512
    const unsigned short* ap = A_s + q * 256 + ln * 8;      // + r*4096 + cc*1024 + rt*128

#define BF(c, tile) (*(const short8*)(bp + (c) * 16384 + (tile) * 512))
#define AF(r, cc, rt) (*(const short8*)(ap + (r) * 4096 + (cc) * 1024 + (rt) * 128))
#define MM(acc, a, b) acc = __builtin_amdgcn_mfma_f32_16x16x32_bf16(a, b, acc, 0, 0, 0)

    f32x4 accI[2][2] = {}, accO[2][2] = {}, accU[2][2] = {}, accFl[2][2] = {}, accFr[2][2] = {};
    const int ti = 2 * w, to = 8 + 2 * w, tu = 16 + 2 * w, tf = 24 + 2 * w;

    #pragma unroll
    for (int c = 0; c < 4; ++c) {      // emb chunks
        short8 bI0 = BF(c, ti), bI1 = BF(c, ti + 1);
        short8 bO0 = BF(c, to), bO1 = BF(c, to + 1);
        short8 bU0 = BF(c, tu), bU1 = BF(c, tu + 1);
        short8 aE0 = AF(0, c, 0), aE1 = AF(0, c, 1);
        MM(accI[0][0], aE0, bI0); MM(accI[0][1], aE0, bI1);
        MM(accI[1][0], aE1, bI0); MM(accI[1][1], aE1, bI1);
        MM(accO[0][0], aE0, bO0); MM(accO[0][1], aE0, bO1);
        MM(accO[1][0], aE1, bO0); MM(accO[1][1], aE1, bO1);
        MM(accU[0][0], aE0, bU0); MM(accU[0][1], aE0, bU1);
        MM(accU[1][0], aE1, bU0); MM(accU[1][1], aE1, bU1);
        if (HC) {
            short8 bF0 = BF(c, tf), bF1 = BF(c, tf + 1);
            MM(accFl[0][0], aE0, bF0); MM(accFl[0][1], aE0, bF1);
            MM(accFl[1][0], aE1, bF0); MM(accFl[1][1], aE1, bF1);
        }
    }
    if (HC) {
        #pragma unroll
        for (int rt = 0; rt < 2; ++rt)
            #pragma unroll
            for (int jt = 0; jt < 2; ++jt)
                accFr[rt][jt] = accFl[rt][jt];      // fork shared x_f
        #pragma unroll
        for (int c = 0; c < 4; ++c) {  // h chunks (bpack chunk 4+c)
            short8 bI0 = BF(4 + c, ti), bI1 = BF(4 + c, ti + 1);
            short8 bO0 = BF(4 + c, to), bO1 = BF(4 + c, to + 1);
            short8 bU0 = BF(4 + c, tu), bU1 = BF(4 + c, tu + 1);
            short8 bF0 = BF(4 + c, tf), bF1 = BF(4 + c, tf + 1);
            short8 aH0 = AF(1, c, 0), aH1 = AF(1, c, 1);
            short8 aL0 = AF(2, c, 0), aL1 = AF(2, c, 1);
            short8 aR0 = AF(3, c, 0), aR1 = AF(3, c, 1);
            MM(accI[0][0], aH0, bI0); MM(accI[0][1], aH0, bI1);
            MM(accI[1][0], aH1, bI0); MM(accI[1][1], aH1, bI1);
            MM(accO[0][0], aH0, bO0); MM(accO[0][1], aH0, bO1);
            MM(accO[1][0], aH1, bO0); MM(accO[1][1], aH1, bO1);
            MM(accU[0][0], aH0, bU0); MM(accU[0][1], aH0, bU1);
            MM(accU[1][0], aH1, bU0); MM(accU[1][1], aH1, bU1);
            MM(accFl[0][0], aL0, bF0); MM(accFl[0][1], aL0, bF1);
            MM(accFl[1][0], aL1, bF0); MM(accFl[1][1], aL1, bF1);
            MM(accFr[0][0], aR0, bF0); MM(accFr[0][1], aR0, bF1);
            MM(accFr[1][0], aR1, bF0); MM(accFr[1][1], aR1, bF1);
        }
    }
#undef BF
#undef AF

    __syncthreads();                 // all A_s reads done; reuse as f32 h_s
    float* h_s = (float*)A_s;        // 32 x 132 f32 (16.9 KB <= 32 KB)

    #pragma unroll
    for (int rt = 0; rt < 2; ++rt) {
        #pragma unroll
        for (int jt = 0; jt < 2; ++jt) {
            const int col = w * 32 + jt * 16 + ln;
            const float bib = biou[col], bob = biou[128 + col], bub = biou[256 + col];
            const float bfb = bfv[col];
            #pragma unroll
            for (int r = 0; r < 4; ++r) {
                const int row = rt * 16 + q * 4 + r;
                const int g = g0 + row;
                const float iv = accI[rt][jt][r] + bib;
                const float ov = accO[rt][jt][r] + bob;
                const float uv = accU[rt][jt][r] + bub;
                float fc = 0.f;
                if (HC) {
                    const float fl = sigm_(accFl[rt][jt][r] + bfb);
                    const float fr = sigm_(accFr[rt][jt][r] + bfb);
                    fc = fl * clp[rt][jt][r] + fr * crp[rt][jt][r];
                }
                const float cc = sigm_(iv) * tanh_(uv) + fc;
                const float hh = sigm_(ov) * tanh_(cc);
                c_ws[(size_t)g * 128 + col] = cc;
                hB[(size_t)g * 128 + col] = f2bf(hh);
                h_s[row * 132 + col] = hh;
            }
        }
    }
    __syncthreads();
    if (t < 160) {                   // output head: 32 nodes x 5 cols, f32
        const int n = t / 5, cc5 = t - 5 * n;
        float acc = bout[cc5];
        #pragma unroll 8
        for (int k = 0; k < 128; ++k) acc += h_s[n * 132 + k] * wout_s[k * 5 + cc5];
        outp[(size_t)(g0 + n) * 5 + cc5] = acc;
    }
}

// ---------------------------------------------------------------------------
// Subtree kernel: block b processes levels d = dTop..dBot for the subtree
// whose dBot-level root is node (2^dBot-1)+b.  dTop-dBot == 4 (16..1 nodes).
// 16-row MFMA tiles; h carried between mini-levels in A_s fragment layout;
// c carried in double-buffered LDS.  All levels here have children.
// A elem (region r, m, k) at r*2048 + (k>>5)*512 + (((k>>3)&3)*16 + m)*8 + (k&7)
// ---------------------------------------------------------------------------
#define MM(acc, a, b) acc = __builtin_amdgcn_mfma_f32_16x16x32_bf16(a, b, acc, 0, 0, 0)
__global__ __launch_bounds__(256) void tree_subtree(
    const int* __restrict__ xids, const int* __restrict__ msk,
    const unsigned short* __restrict__ embB, const unsigned short* __restrict__ bpack,
    const float* __restrict__ biou, const float* __restrict__ bfv,
    const float* __restrict__ Wout, const float* __restrict__ bout,
    unsigned short* __restrict__ hB, float* __restrict__ c_ws, float* __restrict__ outp,
    int dTop, int dBot)
{
    __shared__ __align__(16) unsigned short A_s[6144];    // 3 x 2048, 12 KB
    __shared__ __align__(16) float cbuf[2][16][128];      // 16 KB
    __shared__ __align__(16) float wout_s[640];

    const int t = threadIdx.x, b = blockIdx.x;
    const int lane = t & 63, w = t >> 6;
    const int ln = lane & 15, q = lane >> 4;

    if (t < 160) ((float4*)wout_s)[t] = ((const float4*)Wout)[t];

    const int col0 = w * 32 + ln, col1 = col0 + 16;
    const float bib0 = biou[col0], bob0 = biou[128 + col0], bub0 = biou[256 + col0], bfb0 = bfv[col0];
    const float bib1 = biou[col1], bob1 = biou[128 + col1], bub1 = biou[256 + col1], bfb1 = bfv[col1];

    const unsigned short* bp = bpack + ln * 32 + q * 8;
    const unsigned short* ap = A_s + (q * 16 + ln) * 8;
    const int ti = 2 * w, to = 8 + 2 * w, tu = 16 + 2 * w, tf = 24 + 2 * w;

    for (int d = dTop; d >= dBot; --d) {
        const int nd = 1 << (d - dBot);
        const int g0 = ((1 << d) - 1) + (b << (d - dBot));
        const int par = (dTop - d) & 1;

        if (t < 128) {   // stage emb (region 0), 16 rows (garbage rows >= nd ok)
            const int m = t >> 3, seg = t & 7;
            const int g = g0 + m;
            const int ei = xids[g] * msk[g];
            const uint4* es = (const uint4*)(embB + (size_t)ei * 128 + seg * 16);
            uint4 e0 = es[0], e1 = es[1];
            const int cc = seg >> 1, q0 = (seg & 1) * 2;
            *(uint4*)&A_s[cc * 512 + (q0 * 16 + m) * 8]       = e0;
            *(uint4*)&A_s[cc * 512 + ((q0 + 1) * 16 + m) * 8] = e1;
        }
        if (d == dTop) {   // stage 32 child h rows from global
            const int row = t >> 3, sg = t & 7;
            const int child = 2 * g0 + 1 + row;
            const uint4* hp = (const uint4*)(hB + (size_t)child * 128 + sg * 16);
            uint4 h0 = hp[0], h1 = hp[1];
            const int reg = 1 + (row & 1), mm = row >> 1;
            const int cc = sg >> 1, q0 = (sg & 1) * 2;
            *(uint4*)&A_s[reg * 2048 + cc * 512 + (q0 * 16 + mm) * 8]       = h0;
            *(uint4*)&A_s[reg * 2048 + cc * 512 + ((q0 + 1) * 16 + mm) * 8] = h1;
        }
        __syncthreads();

        f32x4 accI[2] = {}, accO[2] = {}, accU[2] = {}, accFl[2] = {}, accFr[2] = {};
#define BF1(c, tile) (*(const short8*)(bp + (c) * 16384 + (tile) * 512))
#define AF1(r, c) (*(const short8*)(ap + (r) * 2048 + (c) * 512))
        #pragma unroll
        for (int c = 0; c < 4; ++c) {
            short8 aE = AF1(0, c);
            MM(accI[0], aE, BF1(c, ti)); MM(accI[1], aE, BF1(c, ti + 1));
            MM(accO[0], aE, BF1(c, to)); MM(accO[1], aE, BF1(c, to + 1));
            MM(accU[0], aE, BF1(c, tu)); MM(accU[1], aE, BF1(c, tu + 1));
            MM(accFl[0], aE, BF1(c, tf)); MM(accFl[1], aE, BF1(c, tf + 1));
        }
        accFr[0] = accFl[0]; accFr[1] = accFl[1];
        #pragma unroll
        for (int c = 0; c < 4; ++c) {
            short8 aL = AF1(1, c), aR = AF1(2, c);
            short8 bI0 = BF1(4 + c, ti), bI1 = BF1(4 + c, ti + 1);
            short8 bO0 = BF1(4 + c, to), bO1 = BF1(4 + c, to + 1);
            short8 bU0 = BF1(4 + c, tu), bU1 = BF1(4 + c, tu + 1);
            short8 bF0 = BF1(4 + c, tf), bF1 = BF1(4 + c, tf + 1);
            MM(accI[0], aL, bI0); MM(accI[0], aR, bI0);
            MM(accI[1], aL, bI1); MM(accI[1], aR, bI1);
            MM(accO[0], aL, bO0); MM(accO[0], aR, bO0);
            MM(accO[1], aL, bO1); MM(accO[1], aR, bO1);
            MM(accU[0], aL, bU0); MM(accU[0], aR, bU0);
            MM(accU[1], aL, bU1); MM(accU[1], aR, bU1);
            MM(accFl[0], aL, bF0); MM(accFl[1], aL, bF1);
            MM(accFr[0], aR, bF0); MM(accFr[1], aR, bF1);
        }
#undef BF1
#undef AF1
        __syncthreads();   // k-loop reads done before epilogue overwrites A_s h

        #pragma unroll
        for (int jt = 0; jt < 2; ++jt) {
            const int col = jt ? col1 : col0;
            const float bib = jt ? bib1 : bib0, bob = jt ? bob1 : bob0;
            const float bub = jt ? bub1 : bub0, bfb = jt ? bfb1 : bfb0;
            const f32x4 aI = accI[jt], aO = accO[jt], aU = accU[jt];
            const f32x4 aFl = accFl[jt], aFr = accFr[jt];
            #pragma unroll
            for (int r = 0; r < 4; ++r) {
                const int row = q * 4 + r;
                const int g = g0 + row;
                float cl, cr;
                if (d == dTop) {
                    cl = c_ws[(size_t)(2 * g + 1) * 128 + col];
                    cr = c_ws[(size_t)(2 * g + 2) * 128 + col];
                } else {
                    cl = cbuf[1 - par][2 * row][col];
                    cr = cbuf[1 - par][2 * row + 1][col];
                }
                const float iv = aI[r] + bib;
                const float ov = aO[r] + bob;
                const float uv = aU[r] + bub;
                const float fl = sigm_(aFl[r] + bfb);
                const float fr = sigm_(aFr[r] + bfb);
                const float cc = sigm_(iv) * tanh_(uv) + fl * cl + fr * cr;
                const float hh = sigm_(ov) * tanh_(cc);
                cbuf[par][row][col] = cc;
                const unsigned short hb = f2bf(hh);
                const int reg = 1 + (row & 1), mm = row >> 1;
                A_s[reg * 2048 + (col >> 5) * 512 + ((((col >> 3) & 3) * 16) + mm) * 8 + (col & 7)] = hb;
                if (row < nd) {
                    c_ws[(size_t)g * 128 + col] = cc;
                    hB[(size_t)g * 128 + col] = hb;
                }
            }
        }
        __syncthreads();
        if (t < nd * 5) {            // output head for this level's nodes
            const int n = t / 5, cc5 = t - 5 * n;
            const int reg = 1 + (n & 1), mm = n >> 1;
            float acc = bout[cc5];
            #pragma unroll 8
            for (int k = 0; k < 128; ++k) {
                const float hv = bf2f(A_s[reg * 2048 + (k >> 5) * 512 + ((((k >> 3) & 3) * 16) + mm) * 8 + (k & 7)]);
                acc += hv * wout_s[k * 5 + cc5];
            }
            outp[(size_t)(g0 + n) * 5 + cc5] = acc;
        }
        __syncthreads();
    }
}
#undef MM

extern "C" void kernel_launch(void* const* d_in, const int* in_sizes, int n_in,
                              void* d_out, int out_size, void* d_ws, size_t ws_size,
                              hipStream_t stream)
{
    (void)in_sizes; (void)n_in; (void)out_size; (void)ws_size;
    const int*   xids = (const int*)d_in[0];
    const int*   msk  = (const int*)d_in[1];
    const float* emb  = (const float*)d_in[2];
    const float* Wiou = (const float*)d_in[3];
    const float* Uiou = (const float*)d_in[4];
    const float* biou = (const float*)d_in[5];
    const float* Wf   = (const float*)d_in[6];
    const float* Uf   = (const float*)d_in[7];
    const float* bfv  = (const float*)d_in[8];
    const float* Wout = (const float*)d_in[9];
    const float* bout = (const float*)d_in[10];
    float* outp = (float*)d_out;

    // workspace: embB (8.2MB) | bpack (0.26MB) | hB (67MB) | c_ws f32 (134MB)
    unsigned short* embB  = (unsigned short*)d_ws;
    unsigned short* bpack = embB + (size_t)32000 * 128;
    unsigned short* hB    = bpack + 131072;
    float*          c_ws  = (float*)(hB + (size_t)NN * 128);

    cvt_emb<<<dim3((32000 * 128 / 4 + 255) / 256), dim3(256), 0, stream>>>(emb, embB, 32000 * 128 / 4);
    build_bpack<<<dim3(131072 / 256), dim3(256), 0, stream>>>(Wiou, Uiou, Wf, Uf, bpack);

    {   // leaf level d = 17
        const int d = DEPTH - 1, s0 = (1 << d) - 1;
        tree_level_mfma<0><<<dim3((1 << d) / 32), dim3(256), 0, stream>>>(
            xids, msk, embB, bpack, biou, bfv, Wout, bout, hB, c_ws, outp, s0);
    }
    for (int d = DEPTH - 2; d >= 10; --d) {
        const int s0 = (1 << d) - 1;
        tree_level_mfma<1><<<dim3((1 << d) / 32), dim3(256), 0, stream>>>(
            xids, msk, embB, bpack, biou, bfv, Wout, bout, hB, c_ws, outp, s0);
    }
    // levels 9..5: 32 subtree blocks; levels 4..0: 1 subtree block
    tree_subtree<<<dim3(32), dim3(256), 0, stream>>>(
        xids, msk, embB, bpack, biou, bfv, Wout, bout, hB, c_ws, outp, 9, 5);
    tree_subtree<<<dim3(1), dim3(256), 0, stream>>>(
        xids, msk, embB, bpack, biou, bfv, Wout, bout, hB, c_ws, outp, 4, 0);
}